// Round 14
// baseline (2699.901 us; speedup 1.0000x reference)
//
#include <hip/hip_runtime.h>
#include <hip/hip_bf16.h>
#include <stdint.h>
#include <stddef.h>

#define T_LEN 512
#define B_SZ  256
#define I_SZ  256
#define H_SZ  1024
#define NGRP  16   // blocks per barrier group (one batch-group)

typedef __attribute__((ext_vector_type(8))) short bf16x8;
typedef __attribute__((ext_vector_type(4))) float f32x4;
typedef __attribute__((ext_vector_type(4))) unsigned int u32x4;
typedef unsigned short u16;
typedef unsigned int   u32;
typedef unsigned long long u64;

__device__ inline u16 f2bf(float f) {
  union { float f; u32 u; } x; x.f = f;
  u32 r = x.u + 0x7fffu + ((x.u >> 16) & 1u);
  return (u16)(r >> 16);
}
__device__ inline u32 bf2pk(u32 a, u32 b) {  // two fp32 bit-patterns -> packed bf16x2
  u32 ra = (a + 0x7fffu + ((a >> 16) & 1u)) >> 16;
  u32 rb = (b + 0x7fffu + ((b >> 16) & 1u)) >> 16;
  return ra | (rb << 16);
}

// keep 8 bf16x8 values pinned in VGPRs (0 instructions)
#define PIN8(B, i) asm volatile("" : "+v"(B[i]), "+v"(B[i+1]), "+v"(B[i+2]), \
    "+v"(B[i+3]), "+v"(B[i+4]), "+v"(B[i+5]), "+v"(B[i+6]), "+v"(B[i+7]))
#define PIN32(B) do { PIN8(B,0); PIN8(B,8); PIN8(B,16); PIN8(B,24); } while (0)

struct GCnt { u32 v; u32 pad[31]; };  // one 128B line per group counter

__global__ __launch_bounds__(256) void cvt_kernel(const float* __restrict__ src,
                                                  u16* __restrict__ dst, int n) {
  int stride = gridDim.x * blockDim.x * 4;
  for (int i = (blockIdx.x * blockDim.x + threadIdx.x) * 4; i < n; i += stride) {
    float4 v = *reinterpret_cast<const float4*>(src + i);
    ushort4 o;
    o.x = f2bf(v.x); o.y = f2bf(v.y); o.z = f2bf(v.z); o.w = f2bf(v.w);
    *reinterpret_cast<ushort4*>(dst + i) = o;
  }
}

// Persistent fused CTRNN. Sync = r12's proven leader-poll counter barrier.
// Staging = SPECULATIVE one-shot atomic loads issued in the post-shadow of the
// PREVIOUS step (latency hidden under the leader poll), validated at the top
// of the step via r13-proven sign-bit parity tags (h >= 0 so bf16 bit 15 is
// free). All tags fresh -> stage RT is off the critical path entirely; any
// stale -> ONE reload (freshness guaranteed by the release barrier; worst
// case == r12). No polling loop ever touches data lines.
__global__ __launch_bounds__(256, 1) void rnn_persistent(
    const float* __restrict__ x, const u16* __restrict__ Win,
    const u16* __restrict__ Whh, const float* __restrict__ b_in,
    const float* __restrict__ b_hh, float* __restrict__ out,
    u16* __restrict__ hb0, u16* __restrict__ hb1, GCnt* __restrict__ cnts) {
  __shared__ __align__(16) u16 As[16 * 1024];      // 32KB h tile, swizzled
  __shared__ __align__(16) u16 Xs[2][16 * 256];    // 2 x 8KB x tiles, swizzled

  const int b   = blockIdx.x;
  const int mg  = ((b & 7) << 1) | ((b >> 3) & 1);  // batch-group
  const int ng  = b >> 4;                           // col-group
  const int bm0 = mg * 16;
  const int bn0 = ng * 64;
  const int tid = threadIdx.x, lane = tid & 63, wid = tid >> 6;
  const int rl  = lane & 15, kq = lane >> 4;

  u32* cnt = &cnts[mg].v;

  // W fragments in registers: W_hh 16 cols x K=1024 + W_in K=256
  const int wcol = bn0 + wid * 16 + rl;
  bf16x8 Breg[32];
#pragma unroll
  for (int kc = 0; kc < 32; ++kc)
    Breg[kc] = *reinterpret_cast<const bf16x8*>(Whh + (size_t)wcol * H_SZ + kc * 32 + kq * 8);
  bf16x8 Wreg[8];
#pragma unroll
  for (int kc = 0; kc < 8; ++kc)
    Wreg[kc] = *reinterpret_cast<const bf16x8*>(Win + (size_t)wcol * I_SZ + kc * 32 + kq * 8);
  PIN32(Breg);
  PIN8(Wreg, 0);

  const int row = bm0 + rl;                  // batch row (D col dim)
  const int c0  = bn0 + wid * 16 + kq * 4;   // 4 consecutive hidden cols (D rows)
  float4 bsum;
#pragma unroll
  for (int r = 0; r < 4; ++r)
    (&bsum.x)[r] = b_in[c0 + r] + b_hh[c0 + r];

  float4 hprev = {0.f, 0.f, 0.f, 0.f};
  const char* Asb = (const char*)As;

  const int wb = (tid & 127) * 16;  // h-stage: in-row byte offset
  const int rb = tid >> 7;          // h-stage: row parity

  const int xc0 = tid * 2;          // x tile: 2 chunks/thread

  u64 pv[16];                       // speculative staging registers

  // prologue: stage x tile for step 0; speculative load of hb0 (memset zeros,
  // stream-ordered before launch -> tag 0 == expected at t=0)
  {
    const float* xs = x;
#pragma unroll
    for (int j = 0; j < 2; ++j) {
      int c  = xc0 + j;
      int r_ = c >> 5;
      int cb = (c & 31) * 16;
      const float* src = xs + (size_t)(bm0 + r_) * I_SZ + (c & 31) * 8;
      float4 f0 = *reinterpret_cast<const float4*>(src);
      float4 f1 = *reinterpret_cast<const float4*>(src + 4);
      u32x4 v;
      v.x = (u32)f2bf(f0.x) | ((u32)f2bf(f0.y) << 16);
      v.y = (u32)f2bf(f0.z) | ((u32)f2bf(f0.w) << 16);
      v.z = (u32)f2bf(f1.x) | ((u32)f2bf(f1.y) << 16);
      v.w = (u32)f2bf(f1.z) | ((u32)f2bf(f1.w) << 16);
      int dst = r_ * 512 + (cb ^ ((r_ & 7) << 4));
      *reinterpret_cast<u32x4*>((char*)Xs[0] + dst) = v;
    }
    const char* h0b = (const char*)hb0;
#pragma unroll
    for (int i = 0; i < 8; ++i) {
      const u64* p = reinterpret_cast<const u64*>(
          h0b + (size_t)(bm0 + 2 * i + rb) * 2048 + wb);
      pv[2 * i]     = __hip_atomic_load(p,     __ATOMIC_RELAXED, __HIP_MEMORY_SCOPE_AGENT);
      pv[2 * i + 1] = __hip_atomic_load(p + 1, __ATOMIC_RELAXED, __HIP_MEMORY_SCOPE_AGENT);
    }
  }
  __syncthreads();

  for (int t = 0; t < T_LEN; ++t) {
    const char* hinb = (const char*)((t & 1) ? hb1 : hb0);
    u16* hout        = (t & 1) ? hb0 : hb1;

    PIN32(Breg);

    // ---- 1. issue x loads for t+1 (plain; latency rides the MFMA phase)
    float4 xf0a, xf0b, xf1a, xf1b;
    if (t < T_LEN - 1) {
      const float* xs = x + (size_t)(t + 1) * (B_SZ * I_SZ);
      {
        int c = xc0, r_ = c >> 5;
        const float* src = xs + (size_t)(bm0 + r_) * I_SZ + (c & 31) * 8;
        xf0a = *reinterpret_cast<const float4*>(src);
        xf0b = *reinterpret_cast<const float4*>(src + 4);
      }
      {
        int c = xc0 + 1, r_ = c >> 5;
        const float* src = xs + (size_t)(bm0 + r_) * I_SZ + (c & 31) * 8;
        xf1a = *reinterpret_cast<const float4*>(src);
        xf1b = *reinterpret_cast<const float4*>(src + 4);
      }
    }

    // ---- 2. resolve staging: tag check in regs; ONE reload if any stale
    // (freshness after the release barrier is guaranteed — r12 semantics)
    {
      const u64 want = ((u64)((t >> 1) & 1)) << 15;
      u64 bad = 0;
#pragma unroll
      for (int i = 0; i < 16; ++i) bad |= (pv[i] ^ want) & 0x8000ull;
      if (bad) {
#pragma unroll
        for (int i = 0; i < 8; ++i) {
          const u64* p = reinterpret_cast<const u64*>(
              hinb + (size_t)(bm0 + 2 * i + rb) * 2048 + wb);
          pv[2 * i]     = __hip_atomic_load(p,     __ATOMIC_RELAXED, __HIP_MEMORY_SCOPE_AGENT);
          pv[2 * i + 1] = __hip_atomic_load(p + 1, __ATOMIC_RELAXED, __HIP_MEMORY_SCOPE_AGENT);
        }
      }
    }
    // clear tags, swizzled ds_write
#pragma unroll
    for (int i = 0; i < 8; ++i) {
      int r_ = 2 * i + rb;
      u64 a = pv[2 * i]     & ~0x8000ull;
      u64 c = pv[2 * i + 1] & ~0x8000ull;
      u32x4 v;
      v.x = (u32)a; v.y = (u32)(a >> 32);
      v.z = (u32)c; v.w = (u32)(c >> 32);
      int dst = r_ * 2048 + (wb ^ ((r_ & 7) << 4));
      *reinterpret_cast<u32x4*>((char*)As + dst) = v;
    }
    __syncthreads();

    PIN32(Breg);

    // ---- 3. MFMA: acc2 (x tile) + acc0/acc1 (h tile)
    f32x4 acc2 = (f32x4){0.f, 0.f, 0.f, 0.f};
    {
      const char* Xb = (const char*)Xs[t & 1];
#pragma unroll
      for (int kc = 0; kc < 8; ++kc) {
        bf16x8 xa = *reinterpret_cast<const bf16x8*>(
            Xb + rl * 512 + ((kc * 64 + kq * 16) ^ ((rl & 7) << 4)));
        acc2 = __builtin_amdgcn_mfma_f32_16x16x32_bf16(Wreg[kc], xa, acc2, 0, 0, 0);
      }
    }
    f32x4 acc0 = (f32x4){0.f, 0.f, 0.f, 0.f};
    f32x4 acc1 = (f32x4){0.f, 0.f, 0.f, 0.f};
#pragma unroll
    for (int kc = 0; kc < 32; kc += 2) {
      bf16x8 a0 = *reinterpret_cast<const bf16x8*>(
          Asb + rl * 2048 + ((kc * 64 + kq * 16) ^ ((rl & 7) << 4)));
      acc0 = __builtin_amdgcn_mfma_f32_16x16x32_bf16(Breg[kc], a0, acc0, 0, 0, 0);
      bf16x8 a1 = *reinterpret_cast<const bf16x8*>(
          Asb + rl * 2048 + (((kc + 1) * 64 + kq * 16) ^ ((rl & 7) << 4)));
      acc1 = __builtin_amdgcn_mfma_f32_16x16x32_bf16(Breg[kc + 1], a1, acc1, 0, 0, 0);
    }

    // ---- 4. epilogue: compute h; tagged 8B atomic h-store (skip last step)
    float hv[4];
#pragma unroll
    for (int r = 0; r < 4; ++r) {
      float pre = acc0[r] + acc1[r] + acc2[r] + (&bsum.x)[r];
      float hn  = fmaxf(pre, 0.f);
      float h   = (&hprev.x)[r] * 0.9f + hn * 0.1f;
      (&hprev.x)[r] = h;
      hv[r] = h;
    }
    if (t < T_LEN - 1) {
      u32 lo = (u32)f2bf(hv[0]) | ((u32)f2bf(hv[1]) << 16);
      u32 hi = (u32)f2bf(hv[2]) | ((u32)f2bf(hv[3]) << 16);
      lo |= ((u32)(((t + 1) >> 1) & 1)) << 15;   // parity tag (r13-proven)
      u64 pk = (u64)lo | ((u64)hi << 32);
      __hip_atomic_store(reinterpret_cast<u64*>(hout + (size_t)row * H_SZ + c0),
                         pk, __ATOMIC_RELAXED, __HIP_MEMORY_SCOPE_AGENT);
    }

    // ---- 5. post: __syncthreads drains h-stores, then one fetch_add/block
    __syncthreads();
    if (t < T_LEN - 1 && tid == 0)
      __hip_atomic_fetch_add(cnt, 1u, __ATOMIC_RELAXED, __HIP_MEMORY_SCOPE_AGENT);

    // ---- 6. post-shadow: out stores, x cvt -> Xs[(t+1)&1]
    float4 ho = {hv[0], hv[1], hv[2], hv[3]};
    *reinterpret_cast<float4*>(out + (size_t)t * (B_SZ * H_SZ) +
                               (size_t)row * H_SZ + c0) = ho;
    if (t == T_LEN - 1)
      *reinterpret_cast<float4*>(out + (size_t)T_LEN * (B_SZ * H_SZ) +
                                 (size_t)row * H_SZ + c0) = ho;

    if (t < T_LEN - 1) {
      char* Xw = (char*)Xs[(t + 1) & 1];
      union { float4 f; u32x4 u; } a0u, a1u, b0u, b1u;
      a0u.f = xf0a; a1u.f = xf0b; b0u.f = xf1a; b1u.f = xf1b;
      {
        int c = xc0, r_ = c >> 5, cb = (c & 31) * 16;
        u32x4 v;
        v.x = bf2pk(a0u.u.x, a0u.u.y); v.y = bf2pk(a0u.u.z, a0u.u.w);
        v.z = bf2pk(a1u.u.x, a1u.u.y); v.w = bf2pk(a1u.u.z, a1u.u.w);
        int dst = r_ * 512 + (cb ^ ((r_ & 7) << 4));
        *reinterpret_cast<u32x4*>(Xw + dst) = v;
      }
      {
        int c = xc0 + 1, r_ = c >> 5, cb = (c & 31) * 16;
        u32x4 v;
        v.x = bf2pk(b0u.u.x, b0u.u.y); v.y = bf2pk(b0u.u.z, b0u.u.w);
        v.z = bf2pk(b1u.u.x, b1u.u.y); v.w = bf2pk(b1u.u.z, b1u.u.w);
        int dst = r_ * 512 + (cb ^ ((r_ & 7) << 4));
        *reinterpret_cast<u32x4*>(Xw + dst) = v;
      }

      // ---- 7. speculative staging loads for t+1, issued LATE (max hit rate);
      // latency hides under the leader poll + release barrier
      const char* hnext = (const char*)hout;   // hin(t+1) == hout(t)
#pragma unroll
      for (int i = 0; i < 8; ++i) {
        const u64* p = reinterpret_cast<const u64*>(
            hnext + (size_t)(bm0 + 2 * i + rb) * 2048 + wb);
        pv[2 * i]     = __hip_atomic_load(p,     __ATOMIC_RELAXED, __HIP_MEMORY_SCOPE_AGENT);
        pv[2 * i + 1] = __hip_atomic_load(p + 1, __ATOMIC_RELAXED, __HIP_MEMORY_SCOPE_AGENT);
      }

      // ---- 8. leader poll + release
      if (tid == 0) {
        const u32 tgt = (u32)(NGRP * (t + 1));
        while (__hip_atomic_load(cnt, __ATOMIC_RELAXED, __HIP_MEMORY_SCOPE_AGENT) < tgt) {
        }
      }
      __syncthreads();
      __builtin_amdgcn_sched_barrier(0);
    }
  }
}

extern "C" void kernel_launch(void* const* d_in, const int* in_sizes, int n_in,
                              void* d_out, int out_size, void* d_ws, size_t ws_size,
                              hipStream_t stream) {
  const float* x    = (const float*)d_in[0];
  const float* W_in = (const float*)d_in[1];
  const float* b_in = (const float*)d_in[2];
  const float* W_hh = (const float*)d_in[3];
  const float* b_hh = (const float*)d_in[4];
  float* out = (float*)d_out;

  // workspace layout (bytes) — no overlaps
  const size_t off_wib = 0;             // 1024*256  bf16 = 524288
  const size_t off_whb = 524288;        // 1024*1024 bf16 = 2097152
  const size_t off_hb0 = 2621440;       // 256*1024  bf16 = 524288
  const size_t off_hb1 = 3145728;
  const size_t off_cnt = 3670016;       // 16 * 128B = 2048
  const size_t need    = 3672064;
  if (ws_size < need) return;

  char* ws = (char*)d_ws;
  u16* wib  = (u16*)(ws + off_wib);
  u16* whb  = (u16*)(ws + off_whb);
  u16* hb0  = (u16*)(ws + off_hb0);
  u16* hb1  = (u16*)(ws + off_hb1);
  GCnt* cnts = (GCnt*)(ws + off_cnt);

  cvt_kernel<<<64,  256, 0, stream>>>(W_in, wib, H_SZ * I_SZ);
  cvt_kernel<<<256, 256, 0, stream>>>(W_hh, whb, H_SZ * H_SZ);
  // hb0 zeroed every launch (tag 0 = expected at t=0), stream-ordered
  hipMemsetAsync(hb0, 0, (size_t)B_SZ * H_SZ * sizeof(u16), stream);
  hipMemsetAsync(cnts, 0, NGRP * sizeof(GCnt), stream);

  rnn_persistent<<<256, 256, 0, stream>>>(x, wib, whb, b_in, b_hh,
                                          out, hb0, hb1, cnts);
}

// Round 15
// 1218.349 us; speedup vs baseline: 2.2160x; 2.2160x over previous
//
#include <hip/hip_runtime.h>
#include <hip/hip_bf16.h>
#include <stdint.h>
#include <stddef.h>

#define T_LEN 512
#define B_SZ  256
#define I_SZ  256
#define H_SZ  1024
#define NGRP  16   // blocks per barrier group (one batch-group)

typedef __attribute__((ext_vector_type(8))) short bf16x8;
typedef __attribute__((ext_vector_type(4))) float f32x4;
typedef __attribute__((ext_vector_type(4))) unsigned int u32x4;
typedef unsigned short u16;
typedef unsigned int   u32;
typedef unsigned long long u64;

__device__ inline u16 f2bf(float f) {
  union { float f; u32 u; } x; x.f = f;
  u32 r = x.u + 0x7fffu + ((x.u >> 16) & 1u);
  return (u16)(r >> 16);
}
__device__ inline u32 bf2pk(u32 a, u32 b) {  // two fp32 bit-patterns -> packed bf16x2
  u32 ra = (a + 0x7fffu + ((a >> 16) & 1u)) >> 16;
  u32 rb = (b + 0x7fffu + ((b >> 16) & 1u)) >> 16;
  return ra | (rb << 16);
}

// keep 8 bf16x8 values pinned in VGPRs (0 instructions)
#define PIN8(B, i) asm volatile("" : "+v"(B[i]), "+v"(B[i+1]), "+v"(B[i+2]), \
    "+v"(B[i+3]), "+v"(B[i+4]), "+v"(B[i+5]), "+v"(B[i+6]), "+v"(B[i+7]))
#define PIN32(B) do { PIN8(B,0); PIN8(B,8); PIN8(B,16); PIN8(B,24); } while (0)

struct GCnt { u32 v; u32 pad[31]; };  // one 128B line per slot

__global__ __launch_bounds__(256) void cvt_kernel(const float* __restrict__ src,
                                                  u16* __restrict__ dst, int n) {
  int stride = gridDim.x * blockDim.x * 4;
  for (int i = (blockIdx.x * blockDim.x + threadIdx.x) * 4; i < n; i += stride) {
    float4 v = *reinterpret_cast<const float4*>(src + i);
    ushort4 o;
    o.x = f2bf(v.x); o.y = f2bf(v.y); o.z = f2bf(v.z); o.w = f2bf(v.w);
    *reinterpret_cast<ushort4*>(dst + i) = o;
  }
}

// Persistent fused CTRNN. Exactly the r12 kernel (proven 1235us) with ONE
// sync change: the shared group counter (16 serialized fetch_add RMWs + 16
// leaders polling one line) is replaced by 16 padded per-block slot lines per
// group. Post = one relaxed atomic STORE per block (parallel, no RMW queue);
// detect = wave 0 polls slot[lane&15] (16 lines x 4 readers — less contention
// per line than 16-on-1). Same primitives, same drain-before-post invariant,
// monotone slots, in-graph memset.
__global__ __launch_bounds__(256, 1) void rnn_persistent(
    const float* __restrict__ x, const u16* __restrict__ Win,
    const u16* __restrict__ Whh, const float* __restrict__ b_in,
    const float* __restrict__ b_hh, float* __restrict__ out,
    u16* __restrict__ hb0, u16* __restrict__ hb1, GCnt* __restrict__ slots_all) {
  __shared__ __align__(16) u16 As[16 * 1024];      // 32KB h tile, swizzled
  __shared__ __align__(16) u16 Xs[2][16 * 256];    // 2 x 8KB x tiles, swizzled

  const int b   = blockIdx.x;
  const int mg  = ((b & 7) << 1) | ((b >> 3) & 1);  // batch-group
  const int ng  = b >> 4;                           // col-group
  const int bm0 = mg * 16;
  const int bn0 = ng * 64;
  const int tid = threadIdx.x, lane = tid & 63, wid = tid >> 6;
  const int rl  = lane & 15, kq = lane >> 4;

  GCnt* slots = slots_all + mg * NGRP;   // 16 padded lines for this group

  // W fragments in registers: W_hh 16 cols x K=1024 + W_in K=256
  const int wcol = bn0 + wid * 16 + rl;
  bf16x8 Breg[32];
#pragma unroll
  for (int kc = 0; kc < 32; ++kc)
    Breg[kc] = *reinterpret_cast<const bf16x8*>(Whh + (size_t)wcol * H_SZ + kc * 32 + kq * 8);
  bf16x8 Wreg[8];
#pragma unroll
  for (int kc = 0; kc < 8; ++kc)
    Wreg[kc] = *reinterpret_cast<const bf16x8*>(Win + (size_t)wcol * I_SZ + kc * 32 + kq * 8);
  PIN32(Breg);
  PIN8(Wreg, 0);

  const int row = bm0 + rl;                  // batch row (D col dim)
  const int c0  = bn0 + wid * 16 + kq * 4;   // 4 consecutive hidden cols (D rows)
  float4 bsum;
#pragma unroll
  for (int r = 0; r < 4; ++r)
    (&bsum.x)[r] = b_in[c0 + r] + b_hh[c0 + r];

  float4 hprev = {0.f, 0.f, 0.f, 0.f};
  const char* Asb = (const char*)As;

  const int wb = (tid & 127) * 16;  // h-stage: in-row byte offset
  const int rb = tid >> 7;          // h-stage: row parity

  // x tile geometry: chunk c = tid*2+j ; row r_=c>>5 ; in-row byte cb=(c&31)*16
  const int xc0 = tid * 2;

  // prologue: stage x tile for step 0 (plain compiler-visible loads)
  {
    const float* xs = x;
#pragma unroll
    for (int j = 0; j < 2; ++j) {
      int c  = xc0 + j;
      int r_ = c >> 5;
      int cb = (c & 31) * 16;
      const float* src = xs + (size_t)(bm0 + r_) * I_SZ + (c & 31) * 8;
      float4 f0 = *reinterpret_cast<const float4*>(src);
      float4 f1 = *reinterpret_cast<const float4*>(src + 4);
      u32x4 v;
      v.x = (u32)f2bf(f0.x) | ((u32)f2bf(f0.y) << 16);
      v.y = (u32)f2bf(f0.z) | ((u32)f2bf(f0.w) << 16);
      v.z = (u32)f2bf(f1.x) | ((u32)f2bf(f1.y) << 16);
      v.w = (u32)f2bf(f1.z) | ((u32)f2bf(f1.w) << 16);
      int dst = r_ * 512 + (cb ^ ((r_ & 7) << 4));
      *reinterpret_cast<u32x4*>((char*)Xs[0] + dst) = v;
    }
  }
  __syncthreads();

  for (int t = 0; t < T_LEN; ++t) {
    const u16* hin = (t & 1) ? hb1 : hb0;
    u16* hout      = (t & 1) ? hb0 : hb1;

    PIN32(Breg);

    // ---- stage h tile: 8 x 16B MALL-coherent loads
    u32x4 sv[8];
    const char* hinb = (const char*)hin;
#pragma unroll
    for (int i = 0; i < 8; ++i) {
      int r_ = 2 * i + rb;
      const void* src = hinb + (size_t)(bm0 + r_) * 2048 + wb;
      asm volatile("global_load_dwordx4 %0, %1, off sc0 sc1"
                   : "=v"(sv[i]) : "v"(src) : "memory");
    }
    // ---- issue x loads for t+1 now (plain cached); they land under MFMA
    u32x4 xv[4];
    if (t < T_LEN - 1) {
      const float* xs = x + (size_t)(t + 1) * (B_SZ * I_SZ);
#pragma unroll
      for (int j = 0; j < 2; ++j) {
        int c = xc0 + j;
        int r_ = c >> 5;
        const void* src = xs + (size_t)(bm0 + r_) * I_SZ + (c & 31) * 8;
        asm volatile("global_load_dwordx4 %0, %1, off"
                     : "=v"(xv[2 * j]) : "v"(src) : "memory");
        asm volatile("global_load_dwordx4 %0, %1, off offset:16"
                     : "=v"(xv[2 * j + 1]) : "v"(src) : "memory");
      }
    }

    // ---- acc2 (x-tile MFMA) computes IN the h-load flight window
    f32x4 acc2 = (f32x4){0.f, 0.f, 0.f, 0.f};
    {
      const char* Xb = (const char*)Xs[t & 1];
#pragma unroll
      for (int kc = 0; kc < 8; ++kc) {
        bf16x8 xa = *reinterpret_cast<const bf16x8*>(
            Xb + rl * 512 + ((kc * 64 + kq * 16) ^ ((rl & 7) << 4)));
        acc2 = __builtin_amdgcn_mfma_f32_16x16x32_bf16(Wreg[kc], xa, acc2, 0, 0, 0);
      }
    }

    if (t < T_LEN - 1) {
      asm volatile("s_waitcnt vmcnt(4)" ::: "memory");  // h done (FIFO), x in flight
    } else {
      asm volatile("s_waitcnt vmcnt(0)" ::: "memory");
    }
    __builtin_amdgcn_sched_barrier(0);   // rule-18: nothing crosses the waitcnt
#pragma unroll
    for (int i = 0; i < 8; ++i) {
      int r_ = 2 * i + rb;
      int dst = r_ * 2048 + (wb ^ ((r_ & 7) << 4));   // proven swizzle
      *reinterpret_cast<u32x4*>((char*)As + dst) = sv[i];
    }
    __syncthreads();   // full barrier (proven)

    PIN32(Breg);

    // ---- MFMA: D = W_hh x h^T (acc2 already done)
    f32x4 acc0 = (f32x4){0.f, 0.f, 0.f, 0.f};
    f32x4 acc1 = (f32x4){0.f, 0.f, 0.f, 0.f};
#pragma unroll
    for (int kc = 0; kc < 32; kc += 2) {
      bf16x8 a0 = *reinterpret_cast<const bf16x8*>(
          Asb + rl * 2048 + ((kc * 64 + kq * 16) ^ ((rl & 7) << 4)));
      acc0 = __builtin_amdgcn_mfma_f32_16x16x32_bf16(Breg[kc], a0, acc0, 0, 0, 0);
      bf16x8 a1 = *reinterpret_cast<const bf16x8*>(
          Asb + rl * 2048 + (((kc + 1) * 64 + kq * 16) ^ ((rl & 7) << 4)));
      acc1 = __builtin_amdgcn_mfma_f32_16x16x32_bf16(Breg[kc + 1], a1, acc1, 0, 0, 0);
    }

    // ---- epilogue: compute h, store bf16 h (agent atomic)
    float hv[4];
#pragma unroll
    for (int r = 0; r < 4; ++r) {
      float pre = acc0[r] + acc1[r] + acc2[r] + (&bsum.x)[r];
      float hn  = fmaxf(pre, 0.f);
      float h   = (&hprev.x)[r] * 0.9f + hn * 0.1f;
      (&hprev.x)[r] = h;
      hv[r] = h;
    }
    u32 lo = (u32)f2bf(hv[0]) | ((u32)f2bf(hv[1]) << 16);
    u32 hi = (u32)f2bf(hv[2]) | ((u32)f2bf(hv[3]) << 16);
    u64 pk = (u64)lo | ((u64)hi << 32);
    __hip_atomic_store(reinterpret_cast<u64*>(hout + (size_t)row * H_SZ + c0), pk,
                       __ATOMIC_RELAXED, __HIP_MEMORY_SCOPE_AGENT);

    // ---- post: __syncthreads drains every wave's vmcnt (h-store acked),
    // then ONE relaxed atomic slot store per block (no RMW serialization)
    __syncthreads();
    if (t < T_LEN - 1 && tid == 0)
      __hip_atomic_store(&slots[ng].v, (u32)(t + 1),
                         __ATOMIC_RELAXED, __HIP_MEMORY_SCOPE_AGENT);

    // ---- post-shadow: x cvt + Xs write (loads landed long ago), out stores
    if (t < T_LEN - 1) {
      asm volatile("s_waitcnt vmcnt(0)" ::: "memory");
      __builtin_amdgcn_sched_barrier(0);   // rule-18: xv uses stay after waitcnt
      char* Xw = (char*)Xs[(t + 1) & 1];
#pragma unroll
      for (int j = 0; j < 2; ++j) {
        int c  = xc0 + j;
        int r_ = c >> 5;
        int cb = (c & 31) * 16;
        u32x4 f0 = xv[2 * j], f1 = xv[2 * j + 1];
        u32x4 v;
        v.x = bf2pk(f0.x, f0.y);
        v.y = bf2pk(f0.z, f0.w);
        v.z = bf2pk(f1.x, f1.y);
        v.w = bf2pk(f1.z, f1.w);
        int dst = r_ * 512 + (cb ^ ((r_ & 7) << 4));
        *reinterpret_cast<u32x4*>(Xw + dst) = v;
      }
    }
    float4 ho = {hv[0], hv[1], hv[2], hv[3]};
    *reinterpret_cast<float4*>(out + (size_t)t * (B_SZ * H_SZ) +
                               (size_t)row * H_SZ + c0) = ho;
    if (t == T_LEN - 1)
      *reinterpret_cast<float4*>(out + (size_t)T_LEN * (B_SZ * H_SZ) +
                                 (size_t)row * H_SZ + c0) = ho;

    // ---- detect: wave 0 polls the 16 slot lines (4 readers/line), release
    if (t < T_LEN - 1) {
      if (tid < 64) {
        for (;;) {
          u32 v = __hip_atomic_load(&slots[lane & 15].v,
                                    __ATOMIC_RELAXED, __HIP_MEMORY_SCOPE_AGENT);
          if (__all(v > (u32)t)) break;
        }
      }
      __syncthreads();
      __builtin_amdgcn_sched_barrier(0);
    }
  }
}

extern "C" void kernel_launch(void* const* d_in, const int* in_sizes, int n_in,
                              void* d_out, int out_size, void* d_ws, size_t ws_size,
                              hipStream_t stream) {
  const float* x    = (const float*)d_in[0];
  const float* W_in = (const float*)d_in[1];
  const float* b_in = (const float*)d_in[2];
  const float* W_hh = (const float*)d_in[3];
  const float* b_hh = (const float*)d_in[4];
  float* out = (float*)d_out;

  // workspace layout (bytes) — no overlaps
  const size_t off_wib = 0;             // 1024*256  bf16 = 524288
  const size_t off_whb = 524288;        // 1024*1024 bf16 = 2097152
  const size_t off_hb0 = 2621440;       // 256*1024  bf16 = 524288
  const size_t off_hb1 = 3145728;
  const size_t off_slt = 3670016;       // 256 slots * 128B = 32768
  const size_t need    = 3702784;
  if (ws_size < need) return;

  char* ws = (char*)d_ws;
  u16* wib  = (u16*)(ws + off_wib);
  u16* whb  = (u16*)(ws + off_whb);
  u16* hb0  = (u16*)(ws + off_hb0);
  u16* hb1  = (u16*)(ws + off_hb1);
  GCnt* slt = (GCnt*)(ws + off_slt);

  cvt_kernel<<<64,  256, 0, stream>>>(W_in, wib, H_SZ * I_SZ);
  cvt_kernel<<<256, 256, 0, stream>>>(W_hh, whb, H_SZ * H_SZ);
  hipMemsetAsync(hb0, 0, (size_t)B_SZ * H_SZ * sizeof(u16), stream);
  hipMemsetAsync(slt, 0, NGRP * NGRP * sizeof(GCnt), stream);

  rnn_persistent<<<256, 256, 0, stream>>>(x, wib, whb, b_in, b_hh,
                                          out, hb0, hb1, slt);
}